// Round 6
// baseline (329.082 us; speedup 1.0000x reference)
//
#include <hip/hip_runtime.h>

// FourierFeatureMLP fused kernel for MI355X (gfx950). Round 6.
//
// vs round 5 (288 us; MfmaUtil 20%, VALUBusy 33%, ~47% latency stall):
//  - Software-pipelined K-loop: ping-pong a/b register sets, fully
//    unrolled; loads for step ks+1 issue before MFMAs of ks. VGPR cap
//    raised to 256 (launch_bounds(256,2)) - LDS-capped at 2 blocks/CU.
//  - Cross-layer prefetch: last K-step prefetches next layer's first
//    a-frags; their L2 latency hides under the tanh epilogue.
//  - Double-buffered hbuf (2 x 32 KB): epilogue writes the other buffer
//    -> ONE barrier per layer (was 2), tanh overlaps MFMA tails.
//
// Layouts (MFMA 16x16x32, learn_hip-verified):
//   A: lane holds A[m=lane&15][k=quad*8+j]  -> W[o][k] row o = base+laneM
//   B: lane holds B[k=quad*8+j][n=lane&15]  -> h[pt=base+laneM][k..k+7]
//   D: n(point)=lane&15, m(hidden unit)=quad*4+reg -> 4 consecutive units.
//
// hbuf swizzle: 16B chunk' = chunk ^ (row&7) breaks the 512-B row-stride
// bank pattern for row-parallel b128 accesses.

#define HDIM   256
#define NFREQ  128
#define NLAYER 8
#define TILE_N 64
#define NTHR   256
#define WELTS  (NLAYER * HDIM * HDIM)

typedef __attribute__((ext_vector_type(8))) _Float16 half8;
typedef __attribute__((ext_vector_type(4))) _Float16 half4;
typedef __attribute__((ext_vector_type(2))) _Float16 half2;
typedef __attribute__((ext_vector_type(4))) float float4v;

__device__ __forceinline__ half2 pk2(float a, float b) {
    return __builtin_bit_cast(half2, __builtin_amdgcn_cvt_pkrtz(a, b));
}

// tanh(acc + b) with pre-scaled bias bK = b * 2/ln2. Saturation-safe.
#define TANH_K 2.885390081777927f
__device__ __forceinline__ float fast_tanh_fused(float acc, float bK) {
    float z = __builtin_amdgcn_exp2f(fmaf(acc, TANH_K, bK));
    float r = __builtin_amdgcn_rcpf(z + 1.0f);
    return fmaf(-2.0f, r, 1.0f);
}

// swizzled LDS element index for h[row][k]
__device__ __forceinline__ int swz(int row, int k) {
    return row * HDIM + ((((k >> 3) ^ (row & 7)) << 3) | (k & 7));
}

// ---- pre-pass: fp32 -> fp16 weights into d_ws (layer 0 = W_in, 1..7 = W_h)
__global__ void convert_w_kernel(const float* __restrict__ W_in,
                                 const float* __restrict__ W_h,
                                 _Float16* __restrict__ dst)
{
    const int i = blockIdx.x * blockDim.x + threadIdx.x;
    const float v = (i < HDIM * HDIM) ? W_in[i] : W_h[i - HDIM * HDIM];
    dst[i] = (_Float16)v;
}

__global__ __launch_bounds__(NTHR, 2)
void ffmlp_kernel(const float* __restrict__ tx,
                  const float* __restrict__ Bf,
                  const _Float16* __restrict__ Wall,
                  const float* __restrict__ b_in,
                  const float* __restrict__ b_h,
                  const float* __restrict__ W_out,
                  const float* __restrict__ b_out,
                  float* __restrict__ out)
{
    __shared__ __align__(16) _Float16 hbuf[2][TILE_N * HDIM]; // 2 x 32 KB

    const int tid  = threadIdx.x;
    const int row0 = blockIdx.x * TILE_N;
    const int lane = tid & 63;
    const int wave = tid >> 6;           // 0..3
    const int nQ    = wave;              // hidden-unit quarter
    const int laneM = lane & 15;
    const int quad  = lane >> 4;

    // ---- issue layer-0 a-frag loads NOW: in flight during stage 1 ----
    half8 a[2][4], b[2][4];
    #pragma unroll
    for (int at = 0; at < 4; ++at) {
        const int o = nQ * 64 + at * 16 + laneM;
        a[0][at] = *(const half8*)&Wall[o * HDIM + quad * 8];
    }

    // ---------------- stage 1: Fourier features -> hbuf[0] ----------------
    // sin(2*pi*r) = v_sin(fract(r)) : argument in revolutions.
    {
        const float2* txv = (const float2*)tx;
        const float4 Bp = *(const float4*)&Bf[4 * lane];   // freq pair
        const int f0 = 2 * lane;
        #pragma unroll 4
        for (int i = 0; i < 16; ++i) {
            const int row = wave * 16 + i;
            const float2 t = txv[row0 + row];
            float r0 = t.x * Bp.x + t.y * Bp.y;            // revolutions
            float r1 = t.x * Bp.z + t.y * Bp.w;
            r0 = __builtin_amdgcn_fractf(r0);
            r1 = __builtin_amdgcn_fractf(r1);
            half2 sp = pk2(__builtin_amdgcn_sinf(r0), __builtin_amdgcn_sinf(r1));
            half2 cp = pk2(__builtin_amdgcn_cosf(r0), __builtin_amdgcn_cosf(r1));
            *(half2*)&hbuf[0][swz(row, f0)]         = sp;
            *(half2*)&hbuf[0][swz(row, f0 + NFREQ)] = cp;
        }
    }
    __syncthreads();

    // ---------------- stage 2: 8 dense layers, ping-pong LDS buffers --------
    for (int layer = 0; layer < NLAYER; ++layer) {
        const _Float16* Wl = Wall + layer * (HDIM * HDIM);
        const _Float16* Wn = Wall + ((layer + 1 < NLAYER) ? layer + 1 : layer) * (HDIM * HDIM);
        const float*    bl = (layer == 0) ? b_in : b_h + (layer - 1) * HDIM;
        const _Float16* rbuf = hbuf[layer & 1];
        _Float16*       wbuf = hbuf[(layer & 1) ^ 1];

        float4v acc[4][4];
        #pragma unroll
        for (int at = 0; at < 4; ++at)
            #pragma unroll
            for (int pt = 0; pt < 4; ++pt)
                acc[at][pt] = (float4v){0.f, 0.f, 0.f, 0.f};

        // initial b-frags (k0 = 0) from the read buffer
        #pragma unroll
        for (int pt = 0; pt < 4; ++pt) {
            const int m = pt * 16 + laneM;
            b[0][pt] = *(const half8*)&rbuf[m * HDIM + ((quad ^ (m & 7)) << 3)];
        }

        // software-pipelined K loop: 8 steps of 32, ping-pong regs.
        // a[0] for ks=0 was prefetched (previous layer's tail / preamble).
        #pragma unroll
        for (int ks = 0; ks < 8; ++ks) {
            const int cur = ks & 1, nxt = cur ^ 1;
            if (ks < 7) {
                const int kk = (ks + 1) * 32 + quad * 8;
                #pragma unroll
                for (int at = 0; at < 4; ++at) {
                    const int o = nQ * 64 + at * 16 + laneM;
                    a[nxt][at] = *(const half8*)&Wl[o * HDIM + kk];
                }
                #pragma unroll
                for (int pt = 0; pt < 4; ++pt) {
                    const int m = pt * 16 + laneM;
                    b[nxt][pt] = *(const half8*)&rbuf[m * HDIM + ((((kk >> 3) ^ (m & 7))) << 3)];
                }
            } else {
                // prefetch NEXT layer's first a-frags; latency hides under tanh
                #pragma unroll
                for (int at = 0; at < 4; ++at) {
                    const int o = nQ * 64 + at * 16 + laneM;
                    a[nxt][at] = *(const half8*)&Wn[o * HDIM + quad * 8];
                }
            }
            #pragma unroll
            for (int at = 0; at < 4; ++at)
                #pragma unroll
                for (int pt = 0; pt < 4; ++pt)
                    acc[at][pt] = __builtin_amdgcn_mfma_f32_16x16x32_f16(
                        a[cur][at], b[cur][pt], acc[at][pt], 0, 0, 0);
        }
        // after ks=7, a[0] holds next layer's k0 frags (ready for next iter)

        // epilogue: fused bias+tanh -> wbuf (other buffer; no pre-barrier)
        #pragma unroll
        for (int at = 0; at < 4; ++at) {
            const int u0 = nQ * 64 + at * 16 + quad * 4;
            float4 b4 = *(const float4*)&bl[u0];
            b4.x *= TANH_K; b4.y *= TANH_K; b4.z *= TANH_K; b4.w *= TANH_K;
            #pragma unroll
            for (int pt = 0; pt < 4; ++pt) {
                const int m = pt * 16 + laneM;
                const float v0 = fast_tanh_fused(acc[at][pt].x, b4.x);
                const float v1 = fast_tanh_fused(acc[at][pt].y, b4.y);
                const float v2 = fast_tanh_fused(acc[at][pt].z, b4.z);
                const float v3 = fast_tanh_fused(acc[at][pt].w, b4.w);
                const half2 lo = pk2(v0, v1);
                const half2 hi = pk2(v2, v3);
                half4 pkv;
                pkv.x = lo.x; pkv.y = lo.y; pkv.z = hi.x; pkv.w = hi.y;
                *(half4*)&wbuf[swz(m, u0)] = pkv;             // ds_write_b64
            }
        }
        __syncthreads();   // single barrier per layer
    }

    // ---------------- stage 3: output matvec (b128 reads, from hbuf[0]) -----
    {
        const int row = tid >> 2;       // 0..63
        const int cq  = tid & 3;
        float sum = 0.f;
        #pragma unroll
        for (int j = 0; j < 8; ++j) {
            const int c = cq * 8 + j;
            const half8 hv = *(const half8*)&hbuf[0][row * HDIM + ((c ^ (row & 7)) << 3)];
            const float4 w0 = *(const float4*)&W_out[c * 8];
            const float4 w1 = *(const float4*)&W_out[c * 8 + 4];
            sum += (float)hv[0] * w0.x + (float)hv[1] * w0.y +
                   (float)hv[2] * w0.z + (float)hv[3] * w0.w +
                   (float)hv[4] * w1.x + (float)hv[5] * w1.y +
                   (float)hv[6] * w1.z + (float)hv[7] * w1.w;
        }
        sum += __shfl_xor(sum, 1);
        sum += __shfl_xor(sum, 2);
        if (cq == 0)
            out[row0 + row] = sum + b_out[0];
    }
}

extern "C" void kernel_launch(void* const* d_in, const int* in_sizes, int n_in,
                              void* d_out, int out_size, void* d_ws, size_t ws_size,
                              hipStream_t stream) {
    const float* tx    = (const float*)d_in[0];
    const float* Bf    = (const float*)d_in[1];
    const float* W_in  = (const float*)d_in[2];
    const float* b_in  = (const float*)d_in[3];
    const float* W_h   = (const float*)d_in[4];
    const float* b_h   = (const float*)d_in[5];
    const float* W_out = (const float*)d_in[6];
    const float* b_out = (const float*)d_in[7];
    float* out = (float*)d_out;

    _Float16* Wall = (_Float16*)d_ws;   // 1 MiB scratch

    const int npts   = in_sizes[0] / 2;
    const int blocks = npts / TILE_N;   // 2048

    convert_w_kernel<<<WELTS / NTHR, NTHR, 0, stream>>>(W_in, W_h, Wall);
    ffmlp_kernel<<<blocks, NTHR, 0, stream>>>(tx, Bf, Wall, b_in, b_h,
                                              W_out, b_out, out);
}